// Round 1
// baseline (108.344 us; speedup 1.0000x reference)
//
#include <hip/hip_runtime.h>
#include <hip/hip_bf16.h>

// Problem constants (P=1 folded out everywhere)
#define NB   8      // batch
#define NA   8      // actions
#define ND   8      // dim_qk
#define NCH  64     // NA*ND q/k channels
#define GT   32     // grid T=H=W
#define KREG 216    // 6^3 halo voxels
#define IMS  40     // im2col/weight row stride in halfwords (80 B)

// LDS pool overlays (bytes):
//  build window: xS[0,2048) BTS[2048,13568) imc[13568,31488)
//  attn  window (round-14 plane layout, kills Phase-C bank conflicts):
//    kPl[0,27648)   : 32 dword-planes [pc][216], pc = a*4 + dpair
//                     read bank = (24*pc + r) % 32 -> <=3-way (vs 8-way before)
//    vPl[27648,31104): 8 half-planes [a][216]
//    qPl[31104,39424): 32 dword-planes [pc][65] (stride 65 = write-conflict pad)
//    PT [39424,40448): per-(lane,wave) action partials, 64x4 f32
#define XS_OFF   0
#define BTS_OFF  2048
#define IMC_OFF  13568
#define KP_OFF   0
#define VP_OFF   27648
#define QP_OFF   31104
#define PT_OFF   39424
#define POOL_SZ  40448    // <= 40960 -> 4 blocks/CU

typedef _Float16 h2_t  __attribute__((ext_vector_type(2)));
typedef _Float16 f16x8 __attribute__((ext_vector_type(8)));
typedef float    f32x4 __attribute__((ext_vector_type(4)));

static __device__ __forceinline__ unsigned pack_h2(float a, float b) {
#if __has_builtin(__builtin_amdgcn_cvt_pkrtz)
    return __builtin_bit_cast(unsigned, __builtin_amdgcn_cvt_pkrtz(a, b));
#else
    unsigned short ha = __builtin_bit_cast(unsigned short, (_Float16)a);
    unsigned short hb = __builtin_bit_cast(unsigned short, (_Float16)b);
    return (unsigned)ha | ((unsigned)hb << 16);
#endif
}

static __device__ __forceinline__ float dot2(unsigned k, unsigned q, float c) {
#if __has_builtin(__builtin_amdgcn_fdot2)
    return __builtin_amdgcn_fdot2(__builtin_bit_cast(h2_t, k),
                                  __builtin_bit_cast(h2_t, q), c, false);
#else
    h2_t a = __builtin_bit_cast(h2_t, k), b = __builtin_bit_cast(h2_t, q);
    return c + (float)a[0] * (float)b[0] + (float)a[1] * (float)b[1];
#endif
}

// Single-dispatch kernel: round-13 phase A (in-block weight build, verified
// cheap) + round-12 per-action phase C (verified 54 us kernel), with
// round-14 plane-major k/v/q LDS layout for conflict-free Phase-C reads.
// THREE-TIMES-CONFIRMED RULE (r9/r13): phase C must keep ONE action's state
// live; merging both actions spills 1 VGPR -> WRITE_SIZE 2->6 MB, +26-35 us.
__launch_bounds__(256, 4)
__global__ void avi_kernel(const float* __restrict__ values,
                           const float* __restrict__ rewards,
                           const float* __restrict__ w_qk,
                           const float* __restrict__ w_v,
                           float* __restrict__ out) {
    __shared__ __align__(16) char pool[POOL_SZ];
    float*    xS   = (float*)(pool + XS_OFF);
    _Float16* BTSl = (_Float16*)(pool + BTS_OFF);
    _Float16* imc  = (_Float16*)(pool + IMC_OFF);
    unsigned* kPl  = (unsigned*)(pool + KP_OFF);
    _Float16* vPl  = (_Float16*)(pool + VP_OFF);
    unsigned* qPl  = (unsigned*)(pool + QP_OFF);

    const int tid  = threadIdx.x;
    const int bb   = blockIdx.x >> 9;      // batch
    const int tile = blockIdx.x & 511;     // 8x8x8 tiles of 4^3
    const int tz = tile >> 6, ty = (tile >> 3) & 7, tx = tile & 7;
    const int g0z = tz * 4, g0y = ty * 4, g0x = tx * 4;
    const int base_in = bb * (GT * GT * GT);

    // ---- Phase A: x staging + in-block weight-image build ----
    for (int i = tid; i < 512; i += 256) {
        int lz = i >> 6, ly = (i >> 3) & 7, lx = i & 7;
        int gz = g0z + lz - 2, gy = g0y + ly - 2, gx = g0x + lx - 2;
        float v = 0.f;
        if ((unsigned)gz < 32u && (unsigned)gy < 32u && (unsigned)gx < 32u) {
            int idx = base_in + gz * 1024 + gy * 32 + gx;
            v = values[idx] + rewards[idx];
        }
        xS[i] = v;
    }
    if (tid < 144) {
        float r[28];
        r[27] = 0.f;
        if (tid < 64) {
            const float* w = w_qk + (NCH + tid) * 27;
            #pragma unroll
            for (int j = 0; j < 27; ++j) r[j] = w[j];
        } else if (tid < 72) {
            int a = tid - 64;
            float m = -1e30f;
            #pragma unroll
            for (int j = 0; j < 27; ++j) { r[j] = w_v[a * 27 + j]; m = fmaxf(m, r[j]); }
            float s = 0.f;
            #pragma unroll
            for (int j = 0; j < 27; ++j) { r[j] = __expf(r[j] - m); s += r[j]; }
            float inv = 1.f / s;
            #pragma unroll
            for (int j = 0; j < 27; ++j) r[j] *= inv;
        } else if (tid < 80) {
            #pragma unroll
            for (int j = 0; j < 27; ++j) r[j] = 0.f;
        } else {
            const float* w = w_qk + (tid - 80) * 27;
            const float L2E = 1.44269504f;
            #pragma unroll
            for (int j = 0; j < 27; ++j) r[j] = w[j] * L2E;
        }
        unsigned* dst = (unsigned*)(BTSl + tid * IMS);
        #pragma unroll
        for (int p = 0; p < 14; ++p) dst[p] = pack_h2(r[2 * p], r[2 * p + 1]);
        #pragma unroll
        for (int p = 14; p < 20; ++p) dst[p] = 0u;
    }
    __syncthreads();

    // ---- Phase B1: im2col fp16 [224][IMS] (OOB voxel columns zeroed) ----
    if (tid < 224) {
        unsigned rowU[16];
        if (tid < KREG) {
            int vz = tid / 36, rem = tid - vz * 36, vy = rem / 6, vx = rem - vy * 6;
            int gz = g0z + vz - 1, gy = g0y + vy - 1, gx = g0x + vx - 1;
            float mask = ((unsigned)gz < 32u && (unsigned)gy < 32u && (unsigned)gx < 32u)
                             ? 1.f : 0.f;
            float xr[27];
            #pragma unroll
            for (int t = 0; t < 27; ++t) {
                int dz = t / 9, dy = (t / 3) % 3, dx = t % 3;
                xr[t] = xS[(vz + dz) * 64 + (vy + dy) * 8 + (vx + dx)] * mask;
            }
            #pragma unroll
            for (int p = 0; p < 13; ++p) rowU[p] = pack_h2(xr[2 * p], xr[2 * p + 1]);
            rowU[13] = pack_h2(xr[26], 0.f);
            rowU[14] = rowU[15] = 0u;
        } else {
            #pragma unroll
            for (int p = 0; p < 16; ++p) rowU[p] = 0u;
        }
        int4* dst = (int4*)((char*)imc + tid * (IMS * 2));
        dst[0] = make_int4(rowU[0], rowU[1], rowU[2], rowU[3]);
        dst[1] = make_int4(rowU[4], rowU[5], rowU[6], rowU[7]);
        dst[2] = make_int4(rowU[8], rowU[9], rowU[10], rowU[11]);
        dst[3] = make_int4(rowU[12], rowU[13], rowU[14], rowU[15]);
    }

    const int lane = tid & 63;
    const int wave = tid >> 6;
    const int quad = lane >> 4;
    const int l15  = lane & 15;

    // A-frags: A[m=l15][k=quad*8+j]; stride 40 halfs -> 2-way (free)
    f16x8 af[9];
    #pragma unroll
    for (int mt = 0; mt < 9; ++mt)
        af[mt] = *(const f16x8*)(BTSl + (mt * 16 + l15) * IMS + quad * 8);

    __syncthreads();   // im2col ready

    f16x8 bf[4];
    #pragma unroll
    for (int i = 0; i < 4; ++i) {
        int nt = wave + i * 4;
        if (nt < 14)
            bf[i] = *(const f16x8*)(imc + (nt * 16 + l15) * IMS + quad * 8);
    }

    __syncthreads();   // frag loads done -> build window reusable as planes

    // ---- Phase B2: unified MFMA; k,v,q -> plane-major LDS ----
    for (int i = 0; i < 4; ++i) {
        int nt = wave + i * 4;
        if (nt >= 14) break;
        int n = nt * 16 + l15;
        bool nvalid = (n < KREG);
        int vz = n / 36, rm = n - vz * 36, vy = rm / 6, vx = rm - vy * 6;
        bool ctr = ((unsigned)(vz - 1) < 4u) && ((unsigned)(vy - 1) < 4u) &&
                   ((unsigned)(vx - 1) < 4u);
        int cvox = (vz - 1) * 16 + (vy - 1) * 4 + (vx - 1);
        #pragma unroll
        for (int mt = 0; mt < 9; ++mt) {
            f32x4 d = __builtin_amdgcn_mfma_f32_16x16x32_f16(
                af[mt], bf[i], (f32x4){0.f, 0.f, 0.f, 0.f}, 0, 0, 0);
            if (mt < 4) {                       // k ch = mt*16 + quad*4 + reg
                if (nvalid) {
                    int pc0 = mt * 8 + quad * 2;
                    kPl[pc0 * 216 + n]       = pack_h2(d[0], d[1]);
                    kPl[(pc0 + 1) * 216 + n] = pack_h2(d[2], d[3]);
                }
            } else if (mt == 4) {               // v actions quad*4+reg (quad<2)
                if (nvalid && quad < 2) {
                    #pragma unroll
                    for (int j = 0; j < 4; ++j)
                        vPl[(quad * 4 + j) * 216 + n] = (_Float16)d[j];
                }
            } else {                            // q ch = (mt-5)*16 + quad*4
                if (ctr) {
                    int pc0 = (mt - 5) * 8 + quad * 2;
                    qPl[pc0 * 65 + cvox]       = pack_h2(d[0], d[1]);
                    qPl[(pc0 + 1) * 65 + cvox] = pack_h2(d[2], d[3]);
                }
            }
        }
    }
    __syncthreads();

    // ---- Phase C: PER-ACTION attention (one action's state live at a time
    // — do not merge, see rule above). Plane-major reads: per-nn offsets are
    // ds_read offset immediates off a single base vreg; banks ~2-way. ----
    const int clz = lane >> 4, cly = (lane >> 2) & 3, clx = lane & 3;
    const int rbase = clz * 36 + cly * 6 + clx;

    float best = -1e30f;
    #pragma unroll
    for (int ti = 0; ti < 2; ++ti) {
        int a = wave + ti * 4;                    // wave-uniform
        unsigned qp[4];
        #pragma unroll
        for (int p = 0; p < 4; ++p)
            qp[p] = qPl[(a * 4 + p) * 65 + lane];   // bank = pc+lane: free
        const unsigned* kA = kPl + a * 4 * 216 + rbase;
        const _Float16* vA = vPl + a * 216 + rbase;
        float ssum = 0.f, acc = 0.f;
        #pragma unroll
        for (int nn = 0; nn < 27; ++nn) {
            int dz = nn / 9, dy = (nn / 3) % 3, dx = nn % 3;
            int off = dz * 36 + dy * 6 + dx;
            float s = dot2(kA[off], qp[0],
                      dot2(kA[off + 216], qp[1],
                      dot2(kA[off + 432], qp[2],
                      dot2(kA[off + 648], qp[3], 0.f))));
            float e = exp2f(s);
            float fv = (float)vA[off];
            ssum += e;
            acc = fmaf(e, fv, acc);
        }
        best = fmaxf(best, acc / ssum);
    }
    ((float*)(pool + PT_OFF))[lane * 4 + wave] = best;
    __syncthreads();

    // ---- max over actions (4 wave-partials) -> fp32 output ----
    if (tid < 64) {
        float4 p = *(const float4*)((const float*)(pool + PT_OFF) + tid * 4);
        float mx = fmaxf(fmaxf(p.x, p.y), fmaxf(p.z, p.w));
        int lz2 = tid >> 4, ly2 = (tid >> 2) & 3, lx2 = tid & 3;
        int o = base_in + (g0z + lz2) * 1024 + (g0y + ly2) * 32 + (g0x + lx2);
        out[o] = mx;
    }
}

extern "C" void kernel_launch(void* const* d_in, const int* in_sizes, int n_in,
                              void* d_out, int out_size, void* d_ws, size_t ws_size,
                              hipStream_t stream) {
    const float* values  = (const float*)d_in[0];
    const float* rewards = (const float*)d_in[1];
    const float* w_qk    = (const float*)d_in[2];
    const float* w_v     = (const float*)d_in[3];
    avi_kernel<<<NB * 512, 256, 0, stream>>>(values, rewards, w_qk, w_v,
                                             (float*)d_out);
}

// Round 2
// 104.183 us; speedup vs baseline: 1.0399x; 1.0399x over previous
//
#include <hip/hip_runtime.h>
#include <hip/hip_bf16.h>

// Problem constants (P=1 folded out everywhere)
#define NB   8      // batch
#define NA   8      // actions
#define ND   8      // dim_qk
#define NCH  64     // NA*ND q/k channels
#define GT   32     // grid T=H=W
#define KREG 216    // 6^3 halo voxels
#define IMS  40     // im2col/weight row stride in halfwords (80 B)

// LDS pool overlays (bytes):
//  build window: xS[0,2048) BTS[2048,13568) imc[13568,31488)
//  attn  window (round-15: action-major planes, 3x fewer phase-C LDS bytes):
//    kAct[0,27648)   : 8 action-planes [216 units x 16B], unit p = n ^ (z&1)
//                      (xor-1 swizzle -> conflict-free b128 reads per 8-lane grp)
//    vPl [27648,32256): 8 action-planes [z:96B][c':16B][8 halfs] (j=0..5 valid)
//    qPl [32256,40576): 32 dword-planes [pc][65] (write-conflict pad, as r14)
//    scratch overlays qPl after q consumed: [a][h][64 vox] float2 = 8192B
#define KACT_OFF 0
#define VP_OFF   27648
#define QP_OFF   32256
#define SC_OFF   32256
#define POOL_SZ  40576    // <= 40960 -> 4 blocks/CU

typedef _Float16 h2_t  __attribute__((ext_vector_type(2)));
typedef _Float16 f16x8 __attribute__((ext_vector_type(8)));
typedef float    f32x4 __attribute__((ext_vector_type(4)));

static __device__ __forceinline__ unsigned pack_h2(float a, float b) {
#if __has_builtin(__builtin_amdgcn_cvt_pkrtz)
    return __builtin_bit_cast(unsigned, __builtin_amdgcn_cvt_pkrtz(a, b));
#else
    unsigned short ha = __builtin_bit_cast(unsigned short, (_Float16)a);
    unsigned short hb = __builtin_bit_cast(unsigned short, (_Float16)b);
    return (unsigned)ha | ((unsigned)hb << 16);
#endif
}

static __device__ __forceinline__ float dot2(unsigned k, unsigned q, float c) {
#if __has_builtin(__builtin_amdgcn_fdot2)
    return __builtin_amdgcn_fdot2(__builtin_bit_cast(h2_t, k),
                                  __builtin_bit_cast(h2_t, q), c, false);
#else
    h2_t a = __builtin_bit_cast(h2_t, k), b = __builtin_bit_cast(h2_t, q);
    return c + (float)a[0] * (float)b[0] + (float)a[1] * (float)b[1];
#endif
}

// Round-15: phase C re-decomposed to cut LDS BYTES (the saturated pipe):
// each thread owns a 4-voxel x-run x 1 action x (dz,dy)-half. Each 16B k-row
// is read ONCE per thread and reused for up to 3 voxels -> k-traffic
// 313kB -> 110kB per block. VALU work per thread unchanged (54 dot8/exp2).
// THREE-TIMES-CONFIRMED RULE (r9/r13): one action's state per thread.
__launch_bounds__(256, 4)
__global__ void avi_kernel(const float* __restrict__ values,
                           const float* __restrict__ rewards,
                           const float* __restrict__ w_qk,
                           const float* __restrict__ w_v,
                           float* __restrict__ out) {
    __shared__ __align__(16) char pool[POOL_SZ];
    float*    xS   = (float*)(pool + 0);
    _Float16* BTSl = (_Float16*)(pool + 2048);
    _Float16* imc  = (_Float16*)(pool + 13568);
    unsigned* qPl  = (unsigned*)(pool + QP_OFF);

    const int tid  = threadIdx.x;
    const int bb   = blockIdx.x >> 9;      // batch
    const int tile = blockIdx.x & 511;     // 8x8x8 tiles of 4^3
    const int tz = tile >> 6, ty = (tile >> 3) & 7, tx = tile & 7;
    const int g0z = tz * 4, g0y = ty * 4, g0x = tx * 4;
    const int base_in = bb * (GT * GT * GT);

    // ---- Phase A: x staging + in-block weight-image build ----
    for (int i = tid; i < 512; i += 256) {
        int lz = i >> 6, ly = (i >> 3) & 7, lx = i & 7;
        int gz = g0z + lz - 2, gy = g0y + ly - 2, gx = g0x + lx - 2;
        float v = 0.f;
        if ((unsigned)gz < 32u && (unsigned)gy < 32u && (unsigned)gx < 32u) {
            int idx = base_in + gz * 1024 + gy * 32 + gx;
            v = values[idx] + rewards[idx];
        }
        xS[i] = v;
    }
    if (tid < 144) {
        float r[28];
        r[27] = 0.f;
        if (tid < 64) {
            const float* w = w_qk + (NCH + tid) * 27;
            #pragma unroll
            for (int j = 0; j < 27; ++j) r[j] = w[j];
        } else if (tid < 72) {
            int a = tid - 64;
            float m = -1e30f;
            #pragma unroll
            for (int j = 0; j < 27; ++j) { r[j] = w_v[a * 27 + j]; m = fmaxf(m, r[j]); }
            float s = 0.f;
            #pragma unroll
            for (int j = 0; j < 27; ++j) { r[j] = __expf(r[j] - m); s += r[j]; }
            float inv = 1.f / s;
            #pragma unroll
            for (int j = 0; j < 27; ++j) r[j] *= inv;
        } else if (tid < 80) {
            #pragma unroll
            for (int j = 0; j < 27; ++j) r[j] = 0.f;
        } else {
            const float* w = w_qk + (tid - 80) * 27;
            const float L2E = 1.44269504f;
            #pragma unroll
            for (int j = 0; j < 27; ++j) r[j] = w[j] * L2E;
        }
        unsigned* dst = (unsigned*)(BTSl + tid * IMS);
        #pragma unroll
        for (int p = 0; p < 14; ++p) dst[p] = pack_h2(r[2 * p], r[2 * p + 1]);
        #pragma unroll
        for (int p = 14; p < 20; ++p) dst[p] = 0u;
    }
    __syncthreads();

    // ---- Phase B1: im2col fp16 [224][IMS] (OOB voxel columns zeroed) ----
    if (tid < 224) {
        unsigned rowU[16];
        if (tid < KREG) {
            int vz = tid / 36, rem = tid - vz * 36, vy = rem / 6, vx = rem - vy * 6;
            int gz = g0z + vz - 1, gy = g0y + vy - 1, gx = g0x + vx - 1;
            float mask = ((unsigned)gz < 32u && (unsigned)gy < 32u && (unsigned)gx < 32u)
                             ? 1.f : 0.f;
            float xr[27];
            #pragma unroll
            for (int t = 0; t < 27; ++t) {
                int dz = t / 9, dy = (t / 3) % 3, dx = t % 3;
                xr[t] = xS[(vz + dz) * 64 + (vy + dy) * 8 + (vx + dx)] * mask;
            }
            #pragma unroll
            for (int p = 0; p < 13; ++p) rowU[p] = pack_h2(xr[2 * p], xr[2 * p + 1]);
            rowU[13] = pack_h2(xr[26], 0.f);
            rowU[14] = rowU[15] = 0u;
        } else {
            #pragma unroll
            for (int p = 0; p < 16; ++p) rowU[p] = 0u;
        }
        int4* dst = (int4*)((char*)imc + tid * (IMS * 2));
        dst[0] = make_int4(rowU[0], rowU[1], rowU[2], rowU[3]);
        dst[1] = make_int4(rowU[4], rowU[5], rowU[6], rowU[7]);
        dst[2] = make_int4(rowU[8], rowU[9], rowU[10], rowU[11]);
        dst[3] = make_int4(rowU[12], rowU[13], rowU[14], rowU[15]);
    }

    const int lane = tid & 63;
    const int wave = tid >> 6;
    const int quad = lane >> 4;
    const int l15  = lane & 15;

    // A-frags: A[m=l15][k=quad*8+j]; stride 40 halfs -> 2-way (free)
    f16x8 af[9];
    #pragma unroll
    for (int mt = 0; mt < 9; ++mt)
        af[mt] = *(const f16x8*)(BTSl + (mt * 16 + l15) * IMS + quad * 8);

    __syncthreads();   // im2col ready

    f16x8 bf[4];
    #pragma unroll
    for (int i = 0; i < 4; ++i) {
        int nt = wave + i * 4;
        if (nt < 14)
            bf[i] = *(const f16x8*)(imc + (nt * 16 + l15) * IMS + quad * 8);
    }

    __syncthreads();   // frag loads done -> build window reusable as planes

    // ---- Phase B2: unified MFMA; k,v,q -> action-major LDS ----
    for (int i = 0; i < 4; ++i) {
        int nt = wave + i * 4;
        if (nt >= 14) break;
        int n = nt * 16 + l15;
        bool nvalid = (n < KREG);
        int vz = n / 36, rm = n - vz * 36, vy = rm / 6, vx = rm - vy * 6;
        bool ctr = ((unsigned)(vz - 1) < 4u) && ((unsigned)(vy - 1) < 4u) &&
                   ((unsigned)(vx - 1) < 4u);
        int cvox = (vz - 1) * 16 + (vy - 1) * 4 + (vx - 1);
        // physical k unit byte offset: (n ^ (z&1)) * 16
        int kp_byte = (n * 16) ^ ((vz & 1) << 4);
        #pragma unroll
        for (int mt = 0; mt < 9; ++mt) {
            f32x4 d = __builtin_amdgcn_mfma_f32_16x16x32_f16(
                af[mt], bf[i], (f32x4){0.f, 0.f, 0.f, 0.f}, 0, 0, 0);
            if (mt < 4) {                       // k ch = mt*16 + quad*4 + reg
                if (nvalid) {
                    int a = mt * 2 + (quad >> 1);       // action plane
                    int2 w2;
                    w2.x = (int)pack_h2(d[0], d[1]);
                    w2.y = (int)pack_h2(d[2], d[3]);
                    *(int2*)(pool + KACT_OFF + a * 3456 + kp_byte + (quad & 1) * 8) = w2;
                }
            } else if (mt == 4) {               // v actions quad*4+reg (quad<2)
                if (nvalid && quad < 2) {
                    #pragma unroll
                    for (int j = 0; j < 4; ++j)
                        *(_Float16*)(pool + VP_OFF + (quad * 4 + j) * 576 +
                                     vz * 96 + vy * 16 + vx * 2) = (_Float16)d[j];
                }
            } else {                            // q ch = (mt-5)*16 + quad*4
                if (ctr) {
                    int pc0 = (mt - 5) * 8 + quad * 2;
                    qPl[pc0 * 65 + cvox]       = pack_h2(d[0], d[1]);
                    qPl[(pc0 + 1) * 65 + cvox] = pack_h2(d[2], d[3]);
                }
            }
        }
    }
    __syncthreads();

    // ---- Phase C: 4-voxel x-run per thread, 1 action, (dz,dy)-half split ----
    const int a    = (tid >> 4) & 7;      // action (wave holds 4 actions)
    const int row  = tid & 15;            // clz2*4 + cly2
    const int h    = tid >> 7;            // wave-pair half (wave-uniform!)
    const int clz2 = row >> 2, cly2 = row & 3;

    // q for the 4 voxels of own action -> 16 VGPRs (bank = 4*row + c: free)
    unsigned qp[4][4];
    #pragma unroll
    for (int x = 0; x < 4; ++x) {
        #pragma unroll
        for (int p = 0; p < 4; ++p)
            qp[x][p] = qPl[(a * 4 + p) * 65 + row * 4 + x];
    }
    __syncthreads();   // qPl fully consumed -> scratch overlay safe

    float ssum[4] = {0.f, 0.f, 0.f, 0.f};
    float acc[4]  = {0.f, 0.f, 0.f, 0.f};
    const char* kbase = pool + KACT_OFF + a * 3456;
    const char* vbase = pool + VP_OFF  + a * 576;

    // One (dz,dy) step: read 6 consecutive halo rows once (xor-swizzled via
    // the two-base-pointer trick -> zero per-read VALU), reuse for 12 dots.
#define STEP(DZ, DY) do {                                                     \
        const int zz = clz2 + (DZ), cc = cly2 + (DY);                         \
        const int zbit = zz & 1;                                              \
        const char* adrA = kbase + zz * 576 + cc * 96 + zbit * 16;            \
        const char* adrB = kbase + zz * 576 + cc * 96 + 16 - zbit * 16;       \
        int4 km[6];                                                           \
        km[0] = *(const int4*)(adrA);                                         \
        km[1] = *(const int4*)(adrB);                                         \
        km[2] = *(const int4*)(adrA + 32);                                    \
        km[3] = *(const int4*)(adrB + 32);                                    \
        km[4] = *(const int4*)(adrA + 64);                                    \
        km[5] = *(const int4*)(adrB + 64);                                    \
        f16x8 vv = *(const f16x8*)(vbase + zz * 96 + cc * 16);                \
        _Pragma("unroll")                                                     \
        for (int x = 0; x < 4; ++x) {                                         \
            _Pragma("unroll")                                                 \
            for (int dx = 0; dx < 3; ++dx) {                                  \
                const int j = x + dx;                                         \
                float s = dot2((unsigned)km[j].x, qp[x][0],                   \
                          dot2((unsigned)km[j].y, qp[x][1],                   \
                          dot2((unsigned)km[j].z, qp[x][2],                   \
                          dot2((unsigned)km[j].w, qp[x][3], 0.f))));          \
                float e = exp2f(s);                                           \
                ssum[x] += e;                                                 \
                acc[x] = fmaf(e, (float)vv[j], acc[x]);                       \
            }                                                                 \
        }                                                                     \
    } while (0)

    if (h == 0) {
        STEP(0, 0); STEP(0, 1); STEP(0, 2); STEP(1, 0);
    } else {
        STEP(1, 1); STEP(1, 2); STEP(2, 0); STEP(2, 1); STEP(2, 2);
    }
#undef STEP

    // partials -> scratch [a][h][64 vox] float2 (banks 2-way on b64: free)
    float2* sc = (float2*)(pool + SC_OFF);
    #pragma unroll
    for (int x = 0; x < 4; ++x)
        sc[(a * 2 + h) * 64 + row * 4 + x] = make_float2(ssum[x], acc[x]);
    __syncthreads();

    // ---- merge halves, softmax-normalize, max over actions -> output ----
    if (tid < 64) {
        float best = -1e30f;
        #pragma unroll
        for (int aa = 0; aa < 8; ++aa) {
            float2 p0 = sc[(aa * 2 + 0) * 64 + tid];
            float2 p1 = sc[(aa * 2 + 1) * 64 + tid];
            best = fmaxf(best, (p0.y + p1.y) / (p0.x + p1.x));
        }
        int lz2 = tid >> 4, ly2 = (tid >> 2) & 3, lx2 = tid & 3;
        int o = base_in + (g0z + lz2) * 1024 + (g0y + ly2) * 32 + (g0x + lx2);
        out[o] = best;
    }
}

extern "C" void kernel_launch(void* const* d_in, const int* in_sizes, int n_in,
                              void* d_out, int out_size, void* d_ws, size_t ws_size,
                              hipStream_t stream) {
    const float* values  = (const float*)d_in[0];
    const float* rewards = (const float*)d_in[1];
    const float* w_qk    = (const float*)d_in[2];
    const float* w_v     = (const float*)d_in[3];
    avi_kernel<<<NB * 512, 256, 0, stream>>>(values, rewards, w_qk, w_v,
                                             (float*)d_out);
}

// Round 3
// 103.229 us; speedup vs baseline: 1.0496x; 1.0092x over previous
//
#include <hip/hip_runtime.h>
#include <hip/hip_bf16.h>

// Problem constants (P=1 folded out everywhere)
#define NB   8      // batch
#define NA   8      // actions
#define ND   8      // dim_qk
#define NCH  64     // NA*ND q/k channels
#define GT   32     // grid T=H=W
#define KREG 216    // 6^3 halo voxels
#define IMS  40     // im2col/weight row stride in halfwords (80 B)

// LDS pool overlays (bytes):
//  build window: xS[0,2304) pad-9 rows; BTS[2304,13824); imc[13824,31744)
//  attn  window (round-16):
//    kAct[0,27648)   : 8 action-planes [216 units x 16B], unit p = n ^ (z&1)
//                      (xor-1 swizzle -> floor-rate b128 reads, verified audit)
//    vPl [27648,32256): 8 action-planes [z:96B][c':16B][8 halfs] (j=0..5 valid)
//    qU  [32256,40448): 64 vox x 8 units x 16B, unit = vox*8 + (a ^ (vox&7))
//                      (xor swizzle -> floor b128 q loads, no pad needed)
//    sc overlays kAct after last STEP (barrier-protected): [vox][17] float2
#define KACT_OFF 0
#define VP_OFF   27648
#define QU_OFF   32256
#define POOL_SZ  40448    // <= 40960 -> 4 blocks/CU

typedef _Float16 h2_t  __attribute__((ext_vector_type(2)));
typedef _Float16 f16x8 __attribute__((ext_vector_type(8)));
typedef float    f32x4 __attribute__((ext_vector_type(4)));

static __device__ __forceinline__ unsigned pack_h2(float a, float b) {
#if __has_builtin(__builtin_amdgcn_cvt_pkrtz)
    return __builtin_bit_cast(unsigned, __builtin_amdgcn_cvt_pkrtz(a, b));
#else
    unsigned short ha = __builtin_bit_cast(unsigned short, (_Float16)a);
    unsigned short hb = __builtin_bit_cast(unsigned short, (_Float16)b);
    return (unsigned)ha | ((unsigned)hb << 16);
#endif
}

static __device__ __forceinline__ float dot2(unsigned k, unsigned q, float c) {
#if __has_builtin(__builtin_amdgcn_fdot2)
    return __builtin_amdgcn_fdot2(__builtin_bit_cast(h2_t, k),
                                  __builtin_bit_cast(h2_t, q), c, false);
#else
    h2_t a = __builtin_bit_cast(h2_t, k), b = __builtin_bit_cast(h2_t, q);
    return c + (float)a[0] * (float)b[0] + (float)a[1] * (float)b[1];
#endif
}

// Round-16: bank-conflict cleanup (q XOR-unit layout, padded xS, scratch
// overlay) + balanced 4.5/4.5 (dz,dy)-step split across wave-pair halves.
// THREE-TIMES-CONFIRMED RULE (r9/r13): one action's state per thread.
__launch_bounds__(256, 4)
__global__ void avi_kernel(const float* __restrict__ values,
                           const float* __restrict__ rewards,
                           const float* __restrict__ w_qk,
                           const float* __restrict__ w_v,
                           float* __restrict__ out) {
    __shared__ __align__(16) char pool[POOL_SZ];
    float*    xS   = (float*)(pool + 0);        // [8][72+?]: z*72 + y*9 + x
    _Float16* BTSl = (_Float16*)(pool + 2304);
    _Float16* imc  = (_Float16*)(pool + 13824);
    char*     qU   = pool + QU_OFF;

    const int tid  = threadIdx.x;
    const int bb   = blockIdx.x >> 9;      // batch
    const int tile = blockIdx.x & 511;     // 8x8x8 tiles of 4^3
    const int tz = tile >> 6, ty = (tile >> 3) & 7, tx = tile & 7;
    const int g0z = tz * 4, g0y = ty * 4, g0x = tx * 4;
    const int base_in = bb * (GT * GT * GT);

    // ---- Phase A: x staging + in-block weight-image build ----
    for (int i = tid; i < 512; i += 256) {
        int lz = i >> 6, ly = (i >> 3) & 7, lx = i & 7;
        int gz = g0z + lz - 2, gy = g0y + ly - 2, gx = g0x + lx - 2;
        float v = 0.f;
        if ((unsigned)gz < 32u && (unsigned)gy < 32u && (unsigned)gx < 32u) {
            int idx = base_in + gz * 1024 + gy * 32 + gx;
            v = values[idx] + rewards[idx];
        }
        xS[lz * 72 + ly * 9 + lx] = v;
    }
    if (tid < 144) {
        float r[28];
        r[27] = 0.f;
        if (tid < 64) {
            const float* w = w_qk + (NCH + tid) * 27;
            #pragma unroll
            for (int j = 0; j < 27; ++j) r[j] = w[j];
        } else if (tid < 72) {
            int a = tid - 64;
            float m = -1e30f;
            #pragma unroll
            for (int j = 0; j < 27; ++j) { r[j] = w_v[a * 27 + j]; m = fmaxf(m, r[j]); }
            float s = 0.f;
            #pragma unroll
            for (int j = 0; j < 27; ++j) { r[j] = __expf(r[j] - m); s += r[j]; }
            float inv = 1.f / s;
            #pragma unroll
            for (int j = 0; j < 27; ++j) r[j] *= inv;
        } else if (tid < 80) {
            #pragma unroll
            for (int j = 0; j < 27; ++j) r[j] = 0.f;
        } else {
            const float* w = w_qk + (tid - 80) * 27;
            const float L2E = 1.44269504f;
            #pragma unroll
            for (int j = 0; j < 27; ++j) r[j] = w[j] * L2E;
        }
        unsigned* dst = (unsigned*)(BTSl + tid * IMS);
        #pragma unroll
        for (int p = 0; p < 14; ++p) dst[p] = pack_h2(r[2 * p], r[2 * p + 1]);
        #pragma unroll
        for (int p = 14; p < 20; ++p) dst[p] = 0u;
    }
    __syncthreads();

    // ---- Phase B1: im2col fp16 [224][IMS] (OOB voxel columns zeroed) ----
    if (tid < 224) {
        unsigned rowU[16];
        if (tid < KREG) {
            int vz = tid / 36, rem = tid - vz * 36, vy = rem / 6, vx = rem - vy * 6;
            int gz = g0z + vz - 1, gy = g0y + vy - 1, gx = g0x + vx - 1;
            float mask = ((unsigned)gz < 32u && (unsigned)gy < 32u && (unsigned)gx < 32u)
                             ? 1.f : 0.f;
            float xr[27];
            #pragma unroll
            for (int t = 0; t < 27; ++t) {
                int dz = t / 9, dy = (t / 3) % 3, dx = t % 3;
                xr[t] = xS[(vz + dz) * 72 + (vy + dy) * 9 + (vx + dx)] * mask;
            }
            #pragma unroll
            for (int p = 0; p < 13; ++p) rowU[p] = pack_h2(xr[2 * p], xr[2 * p + 1]);
            rowU[13] = pack_h2(xr[26], 0.f);
            rowU[14] = rowU[15] = 0u;
        } else {
            #pragma unroll
            for (int p = 0; p < 16; ++p) rowU[p] = 0u;
        }
        int4* dst = (int4*)((char*)imc + tid * (IMS * 2));
        dst[0] = make_int4(rowU[0], rowU[1], rowU[2], rowU[3]);
        dst[1] = make_int4(rowU[4], rowU[5], rowU[6], rowU[7]);
        dst[2] = make_int4(rowU[8], rowU[9], rowU[10], rowU[11]);
        dst[3] = make_int4(rowU[12], rowU[13], rowU[14], rowU[15]);
    }

    const int lane = tid & 63;
    const int wave = tid >> 6;
    const int quad = lane >> 4;
    const int l15  = lane & 15;

    // A-frags: A[m=l15][k=quad*8+j]; stride 40 halfs -> floor (audited)
    f16x8 af[9];
    #pragma unroll
    for (int mt = 0; mt < 9; ++mt)
        af[mt] = *(const f16x8*)(BTSl + (mt * 16 + l15) * IMS + quad * 8);

    __syncthreads();   // im2col ready

    f16x8 bf[4];
    #pragma unroll
    for (int i = 0; i < 4; ++i) {
        int nt = wave + i * 4;
        if (nt < 14)
            bf[i] = *(const f16x8*)(imc + (nt * 16 + l15) * IMS + quad * 8);
    }

    __syncthreads();   // frag loads done -> build window reusable as planes

    // ---- Phase B2: unified MFMA; k,v,q -> swizzled LDS ----
    for (int i = 0; i < 4; ++i) {
        int nt = wave + i * 4;
        if (nt >= 14) break;
        int n = nt * 16 + l15;
        bool nvalid = (n < KREG);
        int vz = n / 36, rm = n - vz * 36, vy = rm / 6, vx = rm - vy * 6;
        bool ctr = ((unsigned)(vz - 1) < 4u) && ((unsigned)(vy - 1) < 4u) &&
                   ((unsigned)(vx - 1) < 4u);
        int cvox = (vz - 1) * 16 + (vy - 1) * 4 + (vx - 1);
        // physical k unit byte offset: (n ^ (z&1)) * 16
        int kp_byte = (n * 16) ^ ((vz & 1) << 4);
        #pragma unroll
        for (int mt = 0; mt < 9; ++mt) {
            f32x4 d = __builtin_amdgcn_mfma_f32_16x16x32_f16(
                af[mt], bf[i], (f32x4){0.f, 0.f, 0.f, 0.f}, 0, 0, 0);
            if (mt < 4) {                       // k ch = mt*16 + quad*4 + reg
                if (nvalid) {
                    int a = mt * 2 + (quad >> 1);       // action plane
                    int2 w2;
                    w2.x = (int)pack_h2(d[0], d[1]);
                    w2.y = (int)pack_h2(d[2], d[3]);
                    *(int2*)(pool + KACT_OFF + a * 3456 + kp_byte + (quad & 1) * 8) = w2;
                }
            } else if (mt == 4) {               // v actions quad*4+reg (quad<2)
                if (nvalid && quad < 2) {
                    #pragma unroll
                    for (int j = 0; j < 4; ++j)
                        *(_Float16*)(pool + VP_OFF + (quad * 4 + j) * 576 +
                                     vz * 96 + vy * 16 + vx * 2) = (_Float16)d[j];
                }
            } else {                            // q ch = (mt-5)*16 + quad*4
                if (ctr) {
                    int aq = (mt - 5) * 2 + (quad >> 1);
                    int unit = cvox * 8 + (aq ^ (cvox & 7));
                    int2 w2;
                    w2.x = (int)pack_h2(d[0], d[1]);
                    w2.y = (int)pack_h2(d[2], d[3]);
                    *(int2*)(qU + unit * 16 + (quad & 1) * 8) = w2;
                }
            }
        }
    }
    __syncthreads();

    // ---- Phase C: 4-voxel x-run per thread, 1 action, balanced step split ----
    const int a    = (tid >> 4) & 7;      // action (wave holds 4 actions)
    const int row  = tid & 15;            // clz2*4 + cly2
    const int h    = tid >> 7;            // wave-pair half (wave-uniform!)
    const int clz2 = row >> 2, cly2 = row & 3;

    // q for the 4 voxels of own action: 4 b128 loads, floor-rate (XOR units)
    unsigned qp[4][4];
    #pragma unroll
    for (int x = 0; x < 4; ++x) {
        int vox = row * 4 + x;
        const int4 qv = *(const int4*)(qU + (vox * 8 + (a ^ (vox & 7))) * 16);
        qp[x][0] = (unsigned)qv.x; qp[x][1] = (unsigned)qv.y;
        qp[x][2] = (unsigned)qv.z; qp[x][3] = (unsigned)qv.w;
    }

    float ssum[4] = {0.f, 0.f, 0.f, 0.f};
    float acc[4]  = {0.f, 0.f, 0.f, 0.f};
    const char* kbase = pool + KACT_OFF + a * 3456;
    const char* vbase = pool + VP_OFF  + a * 576;

    // Full (dz,dy) step: 6 halo rows read once (xor two-pointer), 12 dots.
#define STEP(DZ, DY) do {                                                     \
        const int zz = clz2 + (DZ), cc = cly2 + (DY);                         \
        const int zbit = zz & 1;                                              \
        const char* adrA = kbase + zz * 576 + cc * 96 + zbit * 16;            \
        const char* adrB = kbase + zz * 576 + cc * 96 + 16 - zbit * 16;       \
        int4 km[6];                                                           \
        km[0] = *(const int4*)(adrA);                                         \
        km[1] = *(const int4*)(adrB);                                         \
        km[2] = *(const int4*)(adrA + 32);                                    \
        km[3] = *(const int4*)(adrB + 32);                                    \
        km[4] = *(const int4*)(adrA + 64);                                    \
        km[5] = *(const int4*)(adrB + 64);                                    \
        f16x8 vv = *(const f16x8*)(vbase + zz * 96 + cc * 16);                \
        float vf[6];                                                          \
        _Pragma("unroll")                                                     \
        for (int j = 0; j < 6; ++j) vf[j] = (float)vv[j];                     \
        _Pragma("unroll")                                                     \
        for (int x = 0; x < 4; ++x) {                                         \
            _Pragma("unroll")                                                 \
            for (int dx = 0; dx < 3; ++dx) {                                  \
                const int j = x + dx;                                         \
                float s = dot2((unsigned)km[j].x, qp[x][0],                   \
                          dot2((unsigned)km[j].y, qp[x][1],                   \
                          dot2((unsigned)km[j].z, qp[x][2],                   \
                          dot2((unsigned)km[j].w, qp[x][3], 0.f))));          \
                float e = exp2f(s);                                           \
                ssum[x] += e;                                                 \
                acc[x] = fmaf(e, vf[j], acc[x]);                              \
            }                                                                 \
        }                                                                     \
    } while (0)

    // Half step: x in {X0,X0+1} only (X0 even), 4 halo rows, 6 dots.
#define HSTEP(DZ, DY, X0) do {                                                \
        const int zz = clz2 + (DZ), cc = cly2 + (DY);                         \
        const int zbit = zz & 1;                                              \
        const char* base = kbase + zz * 576 + cc * 96 + (X0) * 16;            \
        const char* adrA = base + zbit * 16;                                  \
        const char* adrB = base + 16 - zbit * 16;                             \
        int4 km[4];                                                           \
        km[0] = *(const int4*)(adrA);                                         \
        km[1] = *(const int4*)(adrB);                                         \
        km[2] = *(const int4*)(adrA + 32);                                    \
        km[3] = *(const int4*)(adrB + 32);                                    \
        f16x8 vv = *(const f16x8*)(vbase + zz * 96 + cc * 16);                \
        float vf[4];                                                          \
        _Pragma("unroll")                                                     \
        for (int j = 0; j < 4; ++j) vf[j] = (float)vv[(X0) + j];              \
        _Pragma("unroll")                                                     \
        for (int x = (X0); x < (X0) + 2; ++x) {                               \
            _Pragma("unroll")                                                 \
            for (int dx = 0; dx < 3; ++dx) {                                  \
                const int j = x + dx - (X0);                                  \
                float s = dot2((unsigned)km[j].x, qp[x][0],                   \
                          dot2((unsigned)km[j].y, qp[x][1],                   \
                          dot2((unsigned)km[j].z, qp[x][2],                   \
                          dot2((unsigned)km[j].w, qp[x][3], 0.f))));          \
                float e = exp2f(s);                                           \
                ssum[x] += e;                                                 \
                acc[x] = fmaf(e, vf[j], acc[x]);                              \
            }                                                                 \
        }                                                                     \
    } while (0)

    if (h == 0) {
        STEP(0, 0); STEP(0, 1); STEP(0, 2); STEP(1, 0); HSTEP(1, 1, 0);
    } else {
        HSTEP(1, 1, 2); STEP(1, 2); STEP(2, 0); STEP(2, 1); STEP(2, 2);
    }
#undef STEP
#undef HSTEP

    // scratch overlays dead kAct region; barrier before the overlay write
    float2* sc = (float2*)pool;
    __syncthreads();
    #pragma unroll
    for (int x = 0; x < 4; ++x)
        sc[(row * 4 + x) * 17 + a * 2 + h] = make_float2(ssum[x], acc[x]);
    __syncthreads();

    // ---- merge halves, softmax-normalize, max over actions -> output ----
    if (tid < 64) {
        float best = -1e30f;
        #pragma unroll
        for (int aa = 0; aa < 8; ++aa) {
            float2 p0 = sc[tid * 17 + aa * 2 + 0];
            float2 p1 = sc[tid * 17 + aa * 2 + 1];
            best = fmaxf(best, (p0.y + p1.y) / (p0.x + p1.x));
        }
        int lz2 = tid >> 4, ly2 = (tid >> 2) & 3, lx2 = tid & 3;
        int o = base_in + (g0z + lz2) * 1024 + (g0y + ly2) * 32 + (g0x + lx2);
        out[o] = best;
    }
}

extern "C" void kernel_launch(void* const* d_in, const int* in_sizes, int n_in,
                              void* d_out, int out_size, void* d_ws, size_t ws_size,
                              hipStream_t stream) {
    const float* values  = (const float*)d_in[0];
    const float* rewards = (const float*)d_in[1];
    const float* w_qk    = (const float*)d_in[2];
    const float* w_v     = (const float*)d_in[3];
    avi_kernel<<<NB * 512, 256, 0, stream>>>(values, rewards, w_qk, w_v,
                                             (float*)d_out);
}